// Round 5
// baseline (278.641 us; speedup 1.0000x reference)
//
#include <hip/hip_runtime.h>
#include <cstdint>

#define NN    1024
#define MM    32
#define NEDGE 32240
#define MROWS 64480   // 2*NEDGE

typedef unsigned short ushort_t;

typedef __bf16 bf16x8 __attribute__((ext_vector_type(8)));
typedef float  floatx4 __attribute__((ext_vector_type(4)));

__device__ __forceinline__ float b2f(ushort_t u) {
    union { unsigned int i; float f; } v; v.i = ((unsigned int)u) << 16; return v.f;
}
__device__ __forceinline__ ushort_t f2b(float f) {
    unsigned int u = __builtin_bit_cast(unsigned int, f);
    u = (u + 0x7FFFu + ((u >> 16) & 1u)) >> 16;
    return (ushort_t)u;
}
// K(i): number of edges before node i
__device__ __forceinline__ int edge_base(int i) {
    return (i <= MM) ? ((i * (i - 1)) >> 1) : (496 + (i - MM) * MM);
}
// edge id e -> (dest i, src j)   [validated round 3]
__device__ __forceinline__ void edge_ij(int e, int& i, int& j) {
    if (e < 496) {
        i = (int)((1.0f + sqrtf(8.0f * (float)e + 1.0f)) * 0.5f);
        while (((i * (i - 1)) >> 1) > e) --i;
        while (((i * (i + 1)) >> 1) <= e) ++i;
        j = e - ((i * (i - 1)) >> 1);
    } else {
        int q = e - 496;
        i = MM + (q >> 5);
        j = i - MM + (q & 31);
    }
}

// ---------------- pack: weight transpose fp32->bf16, plus nodes/edges bf16 conversion ----------------
__global__ void k_pack(const float* an1, const float* an2, const float* ae1,
                       const float* ae2, const float* le1, const float* le2,
                       const float* ln1, const float* ln2,
                       const float* nodes, const float* edges,
                       ushort_t* pan1, ushort_t* pan2, ushort_t* pae1, ushort_t* pae2,
                       ushort_t* ple1, ushort_t* ple2, ushort_t* pln1, ushort_t* pln2,
                       ushort_t* nodesb, ushort_t* edgesb) {
    int idx = blockIdx.x * 256 + threadIdx.x;   // 0..704255 exactly (grid 2751*256)
    if (idx < 155648) {
        const float* s; ushort_t* d; int K, N, off;
        if (idx < 40960)       { s = an1; d = pan1; K = 160; N = 256; off = idx;          }
        else if (idx < 73728)  { s = an2; d = pan2; K = 256; N = 128; off = idx - 40960;  }
        else if (idx < 86016)  { s = ae1; d = pae1; K = 96;  N = 128; off = idx - 73728;  }
        else if (idx < 94208)  { s = ae2; d = pae2; K = 128; N = 64;  off = idx - 86016;  }
        else if (idx < 103424) { s = le1; d = ple1; K = 96;  N = 96;  off = idx - 94208;  }
        else if (idx < 106496) { s = le2; d = ple2; K = 96;  N = 32;  off = idx - 103424; }
        else if (idx < 143360) { s = ln1; d = pln1; K = 192; N = 192; off = idx - 106496; }
        else                   { s = ln2; d = pln2; K = 192; N = 64;  off = idx - 143360; }
        int n = off / K, k = off - n * K;
        d[off] = f2b(s[k * N + n]);
    } else {
        const float* s; ushort_t* d; int i4;
        if (idx < 188416) { s = nodes; d = nodesb; i4 = idx - 155648; }   // 32768 threads
        else              { s = edges; d = edgesb; i4 = idx - 188416; }   // 515840 threads
        float4 v = ((const float4*)s)[i4];
        uint2 o;
        o.x = (unsigned)f2b(v.x) | ((unsigned)f2b(v.y) << 16);
        o.y = (unsigned)f2b(v.z) | ((unsigned)f2b(v.w) << 16);
        ((uint2*)d)[i4] = o;
    }
}

// ---------------- fuse1: gather(bf16 uint4 copies) + an1 (160->256) + ae1 (96->128) ----------------
// H1n tight pitch 256, H1e tight pitch 128; coalesced epilogue via LDS transpose.
__global__ __launch_bounds__(384) void k_fuse1(
        const ushort_t* __restrict__ nodesb, const ushort_t* __restrict__ edgesb,
        const ushort_t* __restrict__ pan1, const float* __restrict__ ban1,
        const ushort_t* __restrict__ pae1, const float* __restrict__ bae1,
        ushort_t* __restrict__ H1n, ushort_t* __restrict__ H1e) {
    __shared__ alignas(16) ushort_t xt[32 * 168];     // X tile (padded), reused for H1e stage (32*136)
    __shared__ alignas(16) ushort_t sn[32 * 264];     // H1n stage (padded)
    const int tid = threadIdx.x;
    const int w = tid >> 6, l = tid & 63, lrow = l & 15, lq = l >> 4;
    const int mt = blockIdx.x;

    // B fragments (waves 0-3 = an1 N=256, waves 4-5 = ae1 N=128)
    bf16x8 bfr[5][4]; float bv[4];
    if (w < 4) {
        int n0 = w * 64;
#pragma unroll
        for (int kt = 0; kt < 5; ++kt)
#pragma unroll
            for (int nt = 0; nt < 4; ++nt)
                bfr[kt][nt] = *(const bf16x8*)(pan1 + (size_t)(n0 + nt * 16 + lrow) * 160 + kt * 32 + lq * 8);
#pragma unroll
        for (int nt = 0; nt < 4; ++nt) bv[nt] = ban1[n0 + nt * 16 + lrow];
    } else {
        int n0 = (w - 4) * 64;
#pragma unroll
        for (int kt = 0; kt < 3; ++kt)
#pragma unroll
            for (int nt = 0; nt < 4; ++nt)
                bfr[kt][nt] = *(const bf16x8*)(pae1 + (size_t)(n0 + nt * 16 + lrow) * 96 + kt * 32 + lq * 8);
#pragma unroll
        for (int nt = 0; nt < 4; ++nt) bv[nt] = bae1[n0 + nt * 16 + lrow];
    }

    // gather: 32 rows x 20 uint4 chunks; row = [nodesb[j](8) | edgesb[e](4) | nodesb[i](8)]
    for (int u = tid; u < 640; u += 384) {
        int row = u / 20, c = u - row * 20;
        int r = mt * 32 + row;
        int b = (r >= NEDGE) ? 1 : 0;
        int e = r - b * NEDGE;
        int i, j; edge_ij(e, i, j);
        const uint4* s;
        if (c < 8)       s = (const uint4*)(nodesb + (size_t)(b * NN + j) * 64) + c;
        else if (c < 12) s = (const uint4*)(edgesb + (size_t)r * 32) + (c - 8);
        else             s = (const uint4*)(nodesb + (size_t)(b * NN + i) * 64) + (c - 12);
        *(uint4*)&xt[row * 168 + c * 8] = *s;
    }
    __syncthreads();

    floatx4 acc[2][4];
    floatx4 zero = {0.f, 0.f, 0.f, 0.f};
#pragma unroll
    for (int s = 0; s < 2; ++s)
#pragma unroll
        for (int nt = 0; nt < 4; ++nt) acc[s][nt] = zero;

    const int KT = (w < 4) ? 5 : 3;
#pragma unroll
    for (int s = 0; s < 2; ++s)
        for (int kt = 0; kt < KT; ++kt) {
            bf16x8 a = *(const bf16x8*)&xt[(s * 16 + lrow) * 168 + kt * 32 + lq * 8];
#pragma unroll
            for (int nt = 0; nt < 4; ++nt)
                acc[s][nt] = __builtin_amdgcn_mfma_f32_16x16x32_bf16(a, bfr[kt][nt], acc[s][nt], 0, 0, 0);
        }
    __syncthreads();   // xt reads done; xt becomes H1e stage

    // stage accumulators (scalar 2B LDS writes), then coalesced uint4 global stores
    if (w < 4) {
#pragma unroll
        for (int s = 0; s < 2; ++s)
#pragma unroll
            for (int nt = 0; nt < 4; ++nt) {
                int col = w * 64 + nt * 16 + lrow;
#pragma unroll
                for (int r_ = 0; r_ < 4; ++r_)
                    sn[(s * 16 + lq * 4 + r_) * 264 + col] = f2b(fmaxf(acc[s][nt][r_] + bv[nt], 0.f));
            }
    } else {
#pragma unroll
        for (int s = 0; s < 2; ++s)
#pragma unroll
            for (int nt = 0; nt < 4; ++nt) {
                int col = (w - 4) * 64 + nt * 16 + lrow;
#pragma unroll
                for (int r_ = 0; r_ < 4; ++r_)
                    xt[(s * 16 + lq * 4 + r_) * 136 + col] = f2b(fmaxf(acc[s][nt][r_] + bv[nt], 0.f));
            }
    }
    __syncthreads();
    // H1n: 32 rows x 32 chunks
    for (int u = tid; u < 1024; u += 384) {
        int row = u >> 5, c = u & 31;
        ((uint4*)(H1n + (size_t)(mt * 32 + row) * 256))[c] = *(const uint4*)&sn[row * 264 + c * 8];
    }
    // H1e: 32 rows x 16 chunks
    for (int u = tid; u < 512; u += 384) {
        int row = u >> 4, c = u & 15;
        ((uint4*)(H1e + (size_t)(mt * 32 + row) * 128))[c] = *(const uint4*)&xt[row * 136 + c * 8];
    }
}

// ---------------- generic tile GEMM body: tight-pitch in/out, padded LDS, coalesced epilogue ----------------
template<int KT, int NT, int WAVES>
__device__ __forceinline__ void gemm_block(const ushort_t* __restrict__ in,
                                           const ushort_t* __restrict__ wp,
                                           const float* __restrict__ bias,
                                           ushort_t* __restrict__ out,
                                           int mt, ushort_t* ldsin, ushort_t* ldstage) {
    constexpr int K = KT * 32;
    constexpr int PINL = K + 8;
    constexpr int NW = WAVES * NT * 16;
    constexpr int POUTL = NW + 8;
    constexpr int CIN = K / 8;    // uint4 chunks per input row
    constexpr int COUT = NW / 8;
    const int tid = threadIdx.x;
    const int w = tid >> 6, l = tid & 63, lrow = l & 15, lq = l >> 4;
    const int n0 = w * (NT * 16);

    bf16x8 bfr[KT][NT]; float bv[NT];
#pragma unroll
    for (int kt = 0; kt < KT; ++kt)
#pragma unroll
        for (int nt = 0; nt < NT; ++nt)
            bfr[kt][nt] = *(const bf16x8*)(wp + (size_t)(n0 + nt * 16 + lrow) * K + kt * 32 + lq * 8);
#pragma unroll
    for (int nt = 0; nt < NT; ++nt) bv[nt] = bias[n0 + nt * 16 + lrow];

    for (int u = tid; u < 32 * CIN; u += WAVES * 64) {
        int row = u / CIN, c = u - row * CIN;
        *(uint4*)&ldsin[row * PINL + c * 8] =
            ((const uint4*)(in + (size_t)(mt * 32 + row) * K))[c];
    }
    __syncthreads();

    floatx4 acc[2][NT];
    floatx4 zero = {0.f, 0.f, 0.f, 0.f};
#pragma unroll
    for (int s = 0; s < 2; ++s)
#pragma unroll
        for (int nt = 0; nt < NT; ++nt) acc[s][nt] = zero;

#pragma unroll
    for (int s = 0; s < 2; ++s)
#pragma unroll
        for (int kt = 0; kt < KT; ++kt) {
            bf16x8 a = *(const bf16x8*)&ldsin[(s * 16 + lrow) * PINL + kt * 32 + lq * 8];
#pragma unroll
            for (int nt = 0; nt < NT; ++nt)
                acc[s][nt] = __builtin_amdgcn_mfma_f32_16x16x32_bf16(a, bfr[kt][nt], acc[s][nt], 0, 0, 0);
        }

#pragma unroll
    for (int s = 0; s < 2; ++s)
#pragma unroll
        for (int nt = 0; nt < NT; ++nt) {
            int col = n0 + nt * 16 + lrow;
#pragma unroll
            for (int r_ = 0; r_ < 4; ++r_)
                ldstage[(s * 16 + lq * 4 + r_) * POUTL + col] = f2b(fmaxf(acc[s][nt][r_] + bv[nt], 0.f));
        }
    __syncthreads();
    for (int u = tid; u < 32 * COUT; u += WAVES * 64) {
        int row = u / COUT, c = u - row * COUT;
        ((uint4*)(out + (size_t)(mt * 32 + row) * NW))[c] = *(const uint4*)&ldstage[row * POUTL + c * 8];
    }
}

// ---------------- fuse2: an2 (256->128) | ae2 (128->64), blockIdx split ----------------
__global__ __launch_bounds__(256) void k_fuse2(
        const ushort_t* __restrict__ H1n, const ushort_t* __restrict__ pan2,
        const float* __restrict__ ban2, ushort_t* __restrict__ hn,
        const ushort_t* __restrict__ H1e, const ushort_t* __restrict__ pae2,
        const float* __restrict__ bae2, ushort_t* __restrict__ he) {
    __shared__ alignas(16) ushort_t ldsin[32 * 264];
    __shared__ alignas(16) ushort_t ldstage[32 * 136];
    if (blockIdx.x < 2015) {
        gemm_block<8, 2, 4>(H1n, pan2, ban2, hn, blockIdx.x, ldsin, ldstage);
    } else {
        gemm_block<4, 1, 4>(H1e, pae2, bae2, he, blockIdx.x - 2015, ldsin, ldstage);
    }
}

// ---------------- fuse3: node_final | edge_prefix (LDS-staged), blockIdx split ----------------
__global__ __launch_bounds__(192) void k_fuse3(
        const ushort_t* __restrict__ hn, const float* __restrict__ nodes,
        const ushort_t* __restrict__ pln1, const float* __restrict__ bln1,
        const ushort_t* __restrict__ pln2, const float* __restrict__ bln2,
        float* __restrict__ out_nodes,
        const ushort_t* __restrict__ he, const ushort_t* __restrict__ edgesb,
        ushort_t* __restrict__ ein) {
    int tid = threadIdx.x;
    if (blockIdx.x < 2048) {
        // node finalize: pn = window mean of hn (pitch 128); out = relu(relu([pn,x]W1+b1)W2+b2)
        int bi = blockIdx.x;
        int b = bi >> 10, i = bi & 1023;
        int t = min(i, MM);
        int base = edge_base(i);
        __shared__ float xin[192];
        __shared__ float h[192];
        if (tid < 128) {
            float s = 0.f;
            const ushort_t* hp = hn + (size_t)(b * NEDGE + base) * 128 + tid;
#pragma unroll 4
            for (int p = 0; p < t; ++p) s += b2f(hp[(size_t)p * 128]);
            xin[tid] = s * (1.0f / (float)max(t, 1));
        } else {
            xin[tid] = nodes[(size_t)(b * NN + i) * 64 + (tid - 128)];
        }
        __syncthreads();
        {
            float a = 0.f;
            const uint4* wv = (const uint4*)(pln1 + (size_t)tid * 192);
#pragma unroll
            for (int k8 = 0; k8 < 24; ++k8) {
                uint4 u = wv[k8];
                const ushort_t* us = (const ushort_t*)&u;
#pragma unroll
                for (int jj = 0; jj < 8; ++jj) a += xin[k8 * 8 + jj] * b2f(us[jj]);
            }
            h[tid] = fmaxf(a + bln1[tid], 0.f);
        }
        __syncthreads();
        if (tid < 64) {
            float a = 0.f;
            const uint4* wv = (const uint4*)(pln2 + (size_t)tid * 192);
#pragma unroll
            for (int k8 = 0; k8 < 24; ++k8) {
                uint4 u = wv[k8];
                const ushort_t* us = (const ushort_t*)&u;
#pragma unroll
                for (int jj = 0; jj < 8; ++jj) a += h[k8 * 8 + jj] * b2f(us[jj]);
            }
            out_nodes[(size_t)(b * NN + i) * 64 + tid] = fmaxf(a + bln2[tid], 0.f);
        }
    } else {
        // edge prefix: stage window into LDS (loads pipelined), then serial prefix on LDS only.
        int bi = blockIdx.x - 2048;
        int b = bi >> 10, i = bi & 1023;
        int t = min(i, MM);
        if (t == 0) return;
        int base = b * NEDGE + edge_base(i);
        __shared__ alignas(16) ushort_t hw[32 * 64];   // he window, pitch 64
        for (int u = tid; u < t * 8; u += 192)
            ((uint4*)hw)[u] = ((const uint4*)he)[(size_t)base * 8 + u];
        __syncthreads();
        if (tid < 64) {
            float run = 0.f;
            for (int p = 0; p < t; ++p) {
                float v = (p == 0) ? 0.f : run / (float)p;
                ein[(size_t)(base + p) * 96 + tid] = f2b(v);
                run += b2f(hw[p * 64 + tid]);
            }
        } else if (tid < 96) {
            int c = tid - 64;
            for (int p = 0; p < t; ++p)
                ein[(size_t)(base + p) * 96 + 64 + c] = edgesb[(size_t)(base + p) * 32 + c];
        }
    }
}

// ---------------- le12: le1 (96->96) -> LDS -> le2 (96->32), fused, fp32 coalesced out ----------------
__global__ __launch_bounds__(192) void k_le12(
        const ushort_t* __restrict__ ein, const ushort_t* __restrict__ ple1,
        const float* __restrict__ ble1, const ushort_t* __restrict__ ple2,
        const float* __restrict__ ble2, float* __restrict__ out_edges) {
    __shared__ alignas(16) ushort_t tin[32 * 104];    // ein tile (padded); reused as fp32 out stage 32*36
    __shared__ alignas(16) ushort_t tmid[32 * 104];
    const int tid = threadIdx.x;
    const int w = tid >> 6, l = tid & 63, lrow = l & 15, lq = l >> 4;
    const int mt = blockIdx.x;

    // stage ein tile: 32 rows x 12 chunks (tight pitch 96 -> padded 104)
    for (int u = tid; u < 384; u += 192) {
        int row = u / 12, c = u - row * 12;
        *(uint4*)&tin[row * 104 + c * 8] = ((const uint4*)(ein + (size_t)(mt * 32 + row) * 96))[c];
    }
    // le1 B frags: 3 waves, NT=2, n0=w*32 ; le2 frags: waves 0-1, NT=1
    bf16x8 fb1[3][2]; float v1[2];
#pragma unroll
    for (int kt = 0; kt < 3; ++kt)
#pragma unroll
        for (int nt = 0; nt < 2; ++nt)
            fb1[kt][nt] = *(const bf16x8*)(ple1 + (size_t)(w * 32 + nt * 16 + lrow) * 96 + kt * 32 + lq * 8);
#pragma unroll
    for (int nt = 0; nt < 2; ++nt) v1[nt] = ble1[w * 32 + nt * 16 + lrow];
    bf16x8 fb2[3]; float v2 = 0.f;
    if (w < 2) {
#pragma unroll
        for (int kt = 0; kt < 3; ++kt)
            fb2[kt] = *(const bf16x8*)(ple2 + (size_t)(w * 16 + lrow) * 96 + kt * 32 + lq * 8);
        v2 = ble2[w * 16 + lrow];
    }
    __syncthreads();

    floatx4 acc[2][2];
    floatx4 zero = {0.f, 0.f, 0.f, 0.f};
#pragma unroll
    for (int s = 0; s < 2; ++s) { acc[s][0] = zero; acc[s][1] = zero; }
#pragma unroll
    for (int s = 0; s < 2; ++s)
#pragma unroll
        for (int kt = 0; kt < 3; ++kt) {
            bf16x8 a = *(const bf16x8*)&tin[(s * 16 + lrow) * 104 + kt * 32 + lq * 8];
#pragma unroll
            for (int nt = 0; nt < 2; ++nt)
                acc[s][nt] = __builtin_amdgcn_mfma_f32_16x16x32_bf16(a, fb1[kt][nt], acc[s][nt], 0, 0, 0);
        }
#pragma unroll
    for (int s = 0; s < 2; ++s)
#pragma unroll
        for (int nt = 0; nt < 2; ++nt) {
            int col = w * 32 + nt * 16 + lrow;
#pragma unroll
            for (int r_ = 0; r_ < 4; ++r_)
                tmid[(s * 16 + lq * 4 + r_) * 104 + col] = f2b(fmaxf(acc[s][nt][r_] + v1[nt], 0.f));
        }
    __syncthreads();

    float* stagef = (float*)tin;   // 32 x 36 fp32 stage (tin reads done)
    if (w < 2) {
        floatx4 a2[2] = {zero, zero};
#pragma unroll
        for (int s = 0; s < 2; ++s)
#pragma unroll
            for (int kt = 0; kt < 3; ++kt) {
                bf16x8 a = *(const bf16x8*)&tmid[(s * 16 + lrow) * 104 + kt * 32 + lq * 8];
                a2[s] = __builtin_amdgcn_mfma_f32_16x16x32_bf16(a, fb2[kt], a2[s], 0, 0, 0);
            }
#pragma unroll
        for (int s = 0; s < 2; ++s) {
            int col = w * 16 + lrow;
#pragma unroll
            for (int r_ = 0; r_ < 4; ++r_)
                stagef[(s * 16 + lq * 4 + r_) * 36 + col] = fmaxf(a2[s][r_] + v2, 0.f);
        }
    }
    __syncthreads();
    // out: 32 rows x 8 uint4 chunks (fp32, tight 32 floats/row)
    for (int u = tid; u < 256; u += 192) {
        int row = u >> 3, c = u & 7;
        ((uint4*)(out_edges + (size_t)(mt * 32 + row) * 32))[c] = *(const uint4*)&stagef[row * 36 + c * 4];
    }
}

extern "C" void kernel_launch(void* const* d_in, const int* in_sizes, int n_in,
                              void* d_out, int out_size, void* d_ws, size_t ws_size,
                              hipStream_t stream) {
    const float* nodes = (const float*)d_in[0];
    const float* edges = (const float*)d_in[1];
    const float* Wan1 = (const float*)d_in[2];  const float* ban1 = (const float*)d_in[3];
    const float* Wan2 = (const float*)d_in[4];  const float* ban2 = (const float*)d_in[5];
    const float* Wln1 = (const float*)d_in[6];  const float* bln1 = (const float*)d_in[7];
    const float* Wln2 = (const float*)d_in[8];  const float* bln2 = (const float*)d_in[9];
    const float* Wae1 = (const float*)d_in[10]; const float* bae1 = (const float*)d_in[11];
    const float* Wae2 = (const float*)d_in[12]; const float* bae2 = (const float*)d_in[13];
    const float* Wle1 = (const float*)d_in[14]; const float* ble1 = (const float*)d_in[15];
    const float* Wle2 = (const float*)d_in[16]; const float* ble2 = (const float*)d_in[17];

    char* ws = (char*)d_ws;
    size_t o = 0;
    auto alloc = [&](size_t bytes) -> void* {
        void* r = ws + o;
        o += (bytes + 255) & ~(size_t)255;
        return r;
    };
    ushort_t* H1n    = (ushort_t*)alloc((size_t)MROWS * 256 * 2);
    ushort_t* hn     = (ushort_t*)alloc((size_t)MROWS * 128 * 2);
    ushort_t* H1e    = (ushort_t*)alloc((size_t)MROWS * 128 * 2);
    ushort_t* he     = (ushort_t*)alloc((size_t)MROWS * 64 * 2);
    ushort_t* ein    = (ushort_t*)alloc((size_t)MROWS * 96 * 2);
    ushort_t* nodesb = (ushort_t*)alloc((size_t)2 * NN * 64 * 2);
    ushort_t* edgesb = (ushort_t*)alloc((size_t)MROWS * 32 * 2);
    ushort_t* pan1 = (ushort_t*)alloc(160 * 256 * 2);
    ushort_t* pan2 = (ushort_t*)alloc(256 * 128 * 2);
    ushort_t* pae1 = (ushort_t*)alloc(96 * 128 * 2);
    ushort_t* pae2 = (ushort_t*)alloc(128 * 64 * 2);
    ushort_t* ple1 = (ushort_t*)alloc(96 * 96 * 2);
    ushort_t* ple2 = (ushort_t*)alloc(96 * 32 * 2);
    ushort_t* pln1 = (ushort_t*)alloc(192 * 192 * 2);
    ushort_t* pln2 = (ushort_t*)alloc(192 * 64 * 2);

    float* out_nodes = (float*)d_out;
    float* out_edges = (float*)d_out + 2 * NN * 64;

    k_pack<<<2751, 256, 0, stream>>>(Wan1, Wan2, Wae1, Wae2, Wle1, Wle2, Wln1, Wln2,
                                     nodes, edges,
                                     pan1, pan2, pae1, pae2, ple1, ple2, pln1, pln2,
                                     nodesb, edgesb);
    k_fuse1<<<2015, 384, 0, stream>>>(nodesb, edgesb, pan1, ban1, pae1, bae1, H1n, H1e);
    k_fuse2<<<4030, 256, 0, stream>>>(H1n, pan2, ban2, hn, H1e, pae2, bae2, he);
    k_fuse3<<<4096, 192, 0, stream>>>(hn, nodes, pln1, bln1, pln2, bln2, out_nodes,
                                      he, edgesb, ein);
    k_le12<<<2015, 192, 0, stream>>>(ein, ple1, ble1, ple2, ble2, out_edges);

    (void)in_sizes; (void)n_in; (void)out_size; (void)ws_size;
}

// Round 6
// 181.625 us; speedup vs baseline: 1.5342x; 1.5342x over previous
//
#include <hip/hip_runtime.h>
#include <cstdint>

#define NN    1024
#define MM    32
#define NEDGE 32240
#define MROWS 64480   // 2*NEDGE

typedef unsigned short ushort_t;

typedef __bf16 bf16x8 __attribute__((ext_vector_type(8)));
typedef float  floatx4 __attribute__((ext_vector_type(4)));

__device__ __forceinline__ float b2f(ushort_t u) {
    union { unsigned int i; float f; } v; v.i = ((unsigned int)u) << 16; return v.f;
}
__device__ __forceinline__ ushort_t f2b(float f) {
    unsigned int u = __builtin_bit_cast(unsigned int, f);
    u = (u + 0x7FFFu + ((u >> 16) & 1u)) >> 16;
    return (ushort_t)u;
}
// K(i): number of edges before node i
__device__ __forceinline__ int edge_base(int i) {
    return (i <= MM) ? ((i * (i - 1)) >> 1) : (496 + (i - MM) * MM);
}
// edge id e -> (dest i, src j)   [validated round 3]
__device__ __forceinline__ void edge_ij(int e, int& i, int& j) {
    if (e < 496) {
        i = (int)((1.0f + sqrtf(8.0f * (float)e + 1.0f)) * 0.5f);
        while (((i * (i - 1)) >> 1) > e) --i;
        while (((i * (i + 1)) >> 1) <= e) ++i;
        j = e - ((i * (i - 1)) >> 1);
    } else {
        int q = e - 496;
        i = MM + (q >> 5);
        j = i - MM + (q & 31);
    }
}

// ---------------- pack: weight transpose fp32->bf16, plus nodes/edges bf16 conversion ----------------
__global__ void k_pack(const float* an1, const float* an2, const float* ae1,
                       const float* ae2, const float* le1, const float* le2,
                       const float* ln1, const float* ln2,
                       const float* nodes, const float* edges,
                       ushort_t* pan1, ushort_t* pan2, ushort_t* pae1, ushort_t* pae2,
                       ushort_t* ple1, ushort_t* ple2, ushort_t* pln1, ushort_t* pln2,
                       ushort_t* nodesb, ushort_t* edgesb) {
    int idx = blockIdx.x * 256 + threadIdx.x;   // 0..704255 exactly (grid 2751*256)
    if (idx < 155648) {
        const float* s; ushort_t* d; int K, N, off;
        if (idx < 40960)       { s = an1; d = pan1; K = 160; N = 256; off = idx;          }
        else if (idx < 73728)  { s = an2; d = pan2; K = 256; N = 128; off = idx - 40960;  }
        else if (idx < 86016)  { s = ae1; d = pae1; K = 96;  N = 128; off = idx - 73728;  }
        else if (idx < 94208)  { s = ae2; d = pae2; K = 128; N = 64;  off = idx - 86016;  }
        else if (idx < 103424) { s = le1; d = ple1; K = 96;  N = 96;  off = idx - 94208;  }
        else if (idx < 106496) { s = le2; d = ple2; K = 96;  N = 32;  off = idx - 103424; }
        else if (idx < 143360) { s = ln1; d = pln1; K = 192; N = 192; off = idx - 106496; }
        else                   { s = ln2; d = pln2; K = 192; N = 64;  off = idx - 143360; }
        int n = off / K, k = off - n * K;
        d[off] = f2b(s[k * N + n]);
    } else {
        const float* s; ushort_t* d; int i4;
        if (idx < 188416) { s = nodes; d = nodesb; i4 = idx - 155648; }   // 32768 threads
        else              { s = edges; d = edgesb; i4 = idx - 188416; }   // 515840 threads
        float4 v = ((const float4*)s)[i4];
        uint2 o;
        o.x = (unsigned)f2b(v.x) | ((unsigned)f2b(v.y) << 16);
        o.y = (unsigned)f2b(v.z) | ((unsigned)f2b(v.w) << 16);
        ((uint2*)d)[i4] = o;
    }
}

// ---------------- node_agg: gather + an1 (160->256, LDS) + an2 (256->128) -> hn ----------------
// Persistent blocks, 8 waves. Gather: wave-per-row contiguous uint loads (round-4 proven).
// Epilogue: direct 2B fragment stores (round-4 proven: no HBM write amplification).
__global__ __launch_bounds__(512) void k_node_agg(
        const ushort_t* __restrict__ nodesb, const ushort_t* __restrict__ edgesb,
        const ushort_t* __restrict__ pan1, const float* __restrict__ ban1,
        const ushort_t* __restrict__ pan2, const float* __restrict__ ban2,
        ushort_t* __restrict__ hn, int mtiles) {
    __shared__ alignas(16) ushort_t xt[32 * 168];   // X tile, pitch 160+8
    __shared__ alignas(16) ushort_t sn[32 * 264];   // H1n tile (bf16), pitch 256+8
    const int tid = threadIdx.x;
    const int w = tid >> 6, l = tid & 63, lrow = l & 15, lq = l >> 4;

    // an1 B-frags: wave w -> cols n0=w*32 (NT=2, KT=5)
    bf16x8 b1[5][2]; float v1[2];
#pragma unroll
    for (int kt = 0; kt < 5; ++kt)
#pragma unroll
        for (int nt = 0; nt < 2; ++nt)
            b1[kt][nt] = *(const bf16x8*)(pan1 + (size_t)(w * 32 + nt * 16 + lrow) * 160 + kt * 32 + lq * 8);
#pragma unroll
    for (int nt = 0; nt < 2; ++nt) v1[nt] = ban1[w * 32 + nt * 16 + lrow];
    // an2 B-frags: wave w -> cols n0=w*16 (NT=1, KT=8)
    bf16x8 b2[8];
#pragma unroll
    for (int kt = 0; kt < 8; ++kt)
        b2[kt] = *(const bf16x8*)(pan2 + (size_t)(w * 16 + lrow) * 256 + kt * 32 + lq * 8);
    float v2 = ban2[w * 16 + lrow];

    floatx4 zero = {0.f, 0.f, 0.f, 0.f};
    for (int mt = blockIdx.x; mt < mtiles; mt += gridDim.x) {
        // gather: wave w handles rows w*4..w*4+3; per row contiguous segments
#pragma unroll
        for (int k = 0; k < 4; ++k) {
            int rr = w * 4 + k;
            int r = mt * 32 + rr;
            int b = (r >= NEDGE) ? 1 : 0;
            int e = r - b * NEDGE;
            int i, j; edge_ij(e, i, j);
            unsigned* xrow = (unsigned*)(xt + rr * 168);
            const unsigned* nj = (const unsigned*)(nodesb + (size_t)(b * NN + j) * 64);
            const unsigned* ni = (const unsigned*)(nodesb + (size_t)(b * NN + i) * 64);
            const unsigned* ee = (const unsigned*)(edgesb + (size_t)r * 32);
            if (l < 32) { xrow[l] = nj[l]; xrow[48 + l] = ni[l]; }
            else if (l < 48) xrow[l] = ee[l - 32];
        }
        __syncthreads();

        // an1: 160 -> 256 (per wave: 32 cols)
        floatx4 acc[2][2];
#pragma unroll
        for (int s = 0; s < 2; ++s) { acc[s][0] = zero; acc[s][1] = zero; }
#pragma unroll
        for (int s = 0; s < 2; ++s)
#pragma unroll
            for (int kt = 0; kt < 5; ++kt) {
                bf16x8 a = *(const bf16x8*)&xt[(s * 16 + lrow) * 168 + kt * 32 + lq * 8];
#pragma unroll
                for (int nt = 0; nt < 2; ++nt)
                    acc[s][nt] = __builtin_amdgcn_mfma_f32_16x16x32_bf16(a, b1[kt][nt], acc[s][nt], 0, 0, 0);
            }
        // stage relu(H1n) tile to LDS (bf16 scalar writes)
#pragma unroll
        for (int s = 0; s < 2; ++s)
#pragma unroll
            for (int nt = 0; nt < 2; ++nt) {
                int col = w * 32 + nt * 16 + lrow;
#pragma unroll
                for (int r_ = 0; r_ < 4; ++r_)
                    sn[(s * 16 + lq * 4 + r_) * 264 + col] = f2b(fmaxf(acc[s][nt][r_] + v1[nt], 0.f));
            }
        __syncthreads();

        // an2: 256 -> 128 (per wave: 16 cols)
        floatx4 a2[2] = {zero, zero};
#pragma unroll
        for (int s = 0; s < 2; ++s)
#pragma unroll
            for (int kt = 0; kt < 8; ++kt) {
                bf16x8 a = *(const bf16x8*)&sn[(s * 16 + lrow) * 264 + kt * 32 + lq * 8];
                a2[s] = __builtin_amdgcn_mfma_f32_16x16x32_bf16(a, b2[kt], a2[s], 0, 0, 0);
            }
        // direct fragment stores to hn (pitch 128)
#pragma unroll
        for (int s = 0; s < 2; ++s) {
            int col = w * 16 + lrow;
#pragma unroll
            for (int r_ = 0; r_ < 4; ++r_)
                hn[(size_t)(mt * 32 + s * 16 + lq * 4 + r_) * 128 + col] = f2b(fmaxf(a2[s][r_] + v2, 0.f));
        }
        __syncthreads();   // protect xt/sn before next tile
    }
}

// ---------------- edge_agg: gather(pairs 96) + ae1 (96->128, LDS) + ae2 (128->64) -> he ----------------
__global__ __launch_bounds__(512) void k_edge_agg(
        const ushort_t* __restrict__ nodesb, const ushort_t* __restrict__ edgesb,
        const ushort_t* __restrict__ pae1, const float* __restrict__ bae1,
        const ushort_t* __restrict__ pae2, const float* __restrict__ bae2,
        ushort_t* __restrict__ he, int mtiles) {
    __shared__ alignas(16) ushort_t xt[32 * 104];   // pairs tile, pitch 96+8
    __shared__ alignas(16) ushort_t se[32 * 136];   // H1e tile, pitch 128+8
    const int tid = threadIdx.x;
    const int w = tid >> 6, l = tid & 63, lrow = l & 15, lq = l >> 4;

    // ae1 B-frags: wave w -> cols n0=w*16 (NT=1, KT=3)
    bf16x8 b1[3];
#pragma unroll
    for (int kt = 0; kt < 3; ++kt)
        b1[kt] = *(const bf16x8*)(pae1 + (size_t)(w * 16 + lrow) * 96 + kt * 32 + lq * 8);
    float v1 = bae1[w * 16 + lrow];
    // ae2 B-frags: waves 0-3 -> cols n0=w*16 (NT=1, KT=4)
    bf16x8 b2[4]; float v2 = 0.f;
    if (w < 4) {
#pragma unroll
        for (int kt = 0; kt < 4; ++kt)
            b2[kt] = *(const bf16x8*)(pae2 + (size_t)(w * 16 + lrow) * 128 + kt * 32 + lq * 8);
        v2 = bae2[w * 16 + lrow];
    }

    floatx4 zero = {0.f, 0.f, 0.f, 0.f};
    for (int mt = blockIdx.x; mt < mtiles; mt += gridDim.x) {
#pragma unroll
        for (int k = 0; k < 4; ++k) {
            int rr = w * 4 + k;
            int r = mt * 32 + rr;
            int b = (r >= NEDGE) ? 1 : 0;
            int e = r - b * NEDGE;
            int i, j; edge_ij(e, i, j);
            (void)i;
            unsigned* xrow = (unsigned*)(xt + rr * 104);
            const unsigned* nj = (const unsigned*)(nodesb + (size_t)(b * NN + j) * 64);
            const unsigned* ee = (const unsigned*)(edgesb + (size_t)r * 32);
            if (l < 32) xrow[l] = nj[l];
            else if (l < 48) xrow[l] = ee[l - 32];
        }
        __syncthreads();

        // ae1: 96 -> 128 (per wave: 16 cols)
        floatx4 acc[2] = {zero, zero};
#pragma unroll
        for (int s = 0; s < 2; ++s)
#pragma unroll
            for (int kt = 0; kt < 3; ++kt) {
                bf16x8 a = *(const bf16x8*)&xt[(s * 16 + lrow) * 104 + kt * 32 + lq * 8];
                acc[s] = __builtin_amdgcn_mfma_f32_16x16x32_bf16(a, b1[kt], acc[s], 0, 0, 0);
            }
#pragma unroll
        for (int s = 0; s < 2; ++s) {
            int col = w * 16 + lrow;
#pragma unroll
            for (int r_ = 0; r_ < 4; ++r_)
                se[(s * 16 + lq * 4 + r_) * 136 + col] = f2b(fmaxf(acc[s][r_] + v1, 0.f));
        }
        __syncthreads();

        // ae2: 128 -> 64 (waves 0-3)
        if (w < 4) {
            floatx4 a2[2] = {zero, zero};
#pragma unroll
            for (int s = 0; s < 2; ++s)
#pragma unroll
                for (int kt = 0; kt < 4; ++kt) {
                    bf16x8 a = *(const bf16x8*)&se[(s * 16 + lrow) * 136 + kt * 32 + lq * 8];
                    a2[s] = __builtin_amdgcn_mfma_f32_16x16x32_bf16(a, b2[kt], a2[s], 0, 0, 0);
                }
#pragma unroll
            for (int s = 0; s < 2; ++s) {
                int col = w * 16 + lrow;
#pragma unroll
                for (int r_ = 0; r_ < 4; ++r_)
                    he[(size_t)(mt * 32 + s * 16 + lq * 4 + r_) * 64 + col] = f2b(fmaxf(a2[s][r_] + v2, 0.f));
            }
        }
        __syncthreads();
    }
}

// ---------------- fuse3: node_final | edge_prefix (LDS-staged), blockIdx split ----------------
__global__ __launch_bounds__(192) void k_fuse3(
        const ushort_t* __restrict__ hn, const float* __restrict__ nodes,
        const ushort_t* __restrict__ pln1, const float* __restrict__ bln1,
        const ushort_t* __restrict__ pln2, const float* __restrict__ bln2,
        float* __restrict__ out_nodes,
        const ushort_t* __restrict__ he, const ushort_t* __restrict__ edgesb,
        ushort_t* __restrict__ ein) {
    int tid = threadIdx.x;
    if (blockIdx.x < 2048) {
        int bi = blockIdx.x;
        int b = bi >> 10, i = bi & 1023;
        int t = min(i, MM);
        int base = edge_base(i);
        __shared__ float xin[192];
        __shared__ float h[192];
        if (tid < 128) {
            float s = 0.f;
            const ushort_t* hp = hn + (size_t)(b * NEDGE + base) * 128 + tid;
#pragma unroll 4
            for (int p = 0; p < t; ++p) s += b2f(hp[(size_t)p * 128]);
            xin[tid] = s * (1.0f / (float)max(t, 1));
        } else {
            xin[tid] = nodes[(size_t)(b * NN + i) * 64 + (tid - 128)];
        }
        __syncthreads();
        {
            float a = 0.f;
            const uint4* wv = (const uint4*)(pln1 + (size_t)tid * 192);
#pragma unroll
            for (int k8 = 0; k8 < 24; ++k8) {
                uint4 u = wv[k8];
                const ushort_t* us = (const ushort_t*)&u;
#pragma unroll
                for (int jj = 0; jj < 8; ++jj) a += xin[k8 * 8 + jj] * b2f(us[jj]);
            }
            h[tid] = fmaxf(a + bln1[tid], 0.f);
        }
        __syncthreads();
        if (tid < 64) {
            float a = 0.f;
            const uint4* wv = (const uint4*)(pln2 + (size_t)tid * 192);
#pragma unroll
            for (int k8 = 0; k8 < 24; ++k8) {
                uint4 u = wv[k8];
                const ushort_t* us = (const ushort_t*)&u;
#pragma unroll
                for (int jj = 0; jj < 8; ++jj) a += h[k8 * 8 + jj] * b2f(us[jj]);
            }
            out_nodes[(size_t)(b * NN + i) * 64 + tid] = fmaxf(a + bln2[tid], 0.f);
        }
    } else {
        // edge prefix: stage window into LDS, then serial prefix on LDS only
        int bi = blockIdx.x - 2048;
        int b = bi >> 10, i = bi & 1023;
        int t = min(i, MM);
        if (t == 0) return;
        int base = b * NEDGE + edge_base(i);
        __shared__ alignas(16) ushort_t hw[32 * 64];
        for (int u = tid; u < t * 8; u += 192)
            ((uint4*)hw)[u] = ((const uint4*)he)[(size_t)base * 8 + u];
        __syncthreads();
        if (tid < 64) {
            float run = 0.f;
            for (int p = 0; p < t; ++p) {
                float v = (p == 0) ? 0.f : run / (float)p;
                ein[(size_t)(base + p) * 96 + tid] = f2b(v);
                run += b2f(hw[p * 64 + tid]);
            }
        } else if (tid < 96) {
            int c = tid - 64;
            for (int p = 0; p < t; ++p)
                ein[(size_t)(base + p) * 96 + 64 + c] = edgesb[(size_t)(base + p) * 32 + c];
        }
    }
}

// ---------------- le12: le1 (96->96) -> LDS -> le2 (96->32), fused, fp32 coalesced out ----------------
__global__ __launch_bounds__(192) void k_le12(
        const ushort_t* __restrict__ ein, const ushort_t* __restrict__ ple1,
        const float* __restrict__ ble1, const ushort_t* __restrict__ ple2,
        const float* __restrict__ ble2, float* __restrict__ out_edges) {
    __shared__ alignas(16) ushort_t tin[32 * 104];
    __shared__ alignas(16) ushort_t tmid[32 * 104];
    const int tid = threadIdx.x;
    const int w = tid >> 6, l = tid & 63, lrow = l & 15, lq = l >> 4;
    const int mt = blockIdx.x;

    // stage ein tile: wave-per-row style contiguous uint loads (96 ushorts = 48 uints/row)
    for (int k = 0; k < 11; ++k) {
        int rr = w * 11 + k;                 // 3 waves x 11 rows covers 0..32 (guard)
        if (rr >= 32) break;
        unsigned* xrow = (unsigned*)(tin + rr * 104);
        const unsigned* src = (const unsigned*)(ein + (size_t)(mt * 32 + rr) * 96);
        if (l < 48) xrow[l] = src[l];
    }
    bf16x8 fb1[3][2]; float v1[2];
#pragma unroll
    for (int kt = 0; kt < 3; ++kt)
#pragma unroll
        for (int nt = 0; nt < 2; ++nt)
            fb1[kt][nt] = *(const bf16x8*)(ple1 + (size_t)(w * 32 + nt * 16 + lrow) * 96 + kt * 32 + lq * 8);
#pragma unroll
    for (int nt = 0; nt < 2; ++nt) v1[nt] = ble1[w * 32 + nt * 16 + lrow];
    bf16x8 fb2[3]; float v2 = 0.f;
    if (w < 2) {
#pragma unroll
        for (int kt = 0; kt < 3; ++kt)
            fb2[kt] = *(const bf16x8*)(ple2 + (size_t)(w * 16 + lrow) * 96 + kt * 32 + lq * 8);
        v2 = ble2[w * 16 + lrow];
    }
    __syncthreads();

    floatx4 acc[2][2];
    floatx4 zero = {0.f, 0.f, 0.f, 0.f};
#pragma unroll
    for (int s = 0; s < 2; ++s) { acc[s][0] = zero; acc[s][1] = zero; }
#pragma unroll
    for (int s = 0; s < 2; ++s)
#pragma unroll
        for (int kt = 0; kt < 3; ++kt) {
            bf16x8 a = *(const bf16x8*)&tin[(s * 16 + lrow) * 104 + kt * 32 + lq * 8];
#pragma unroll
            for (int nt = 0; nt < 2; ++nt)
                acc[s][nt] = __builtin_amdgcn_mfma_f32_16x16x32_bf16(a, fb1[kt][nt], acc[s][nt], 0, 0, 0);
        }
#pragma unroll
    for (int s = 0; s < 2; ++s)
#pragma unroll
        for (int nt = 0; nt < 2; ++nt) {
            int col = w * 32 + nt * 16 + lrow;
#pragma unroll
            for (int r_ = 0; r_ < 4; ++r_)
                tmid[(s * 16 + lq * 4 + r_) * 104 + col] = f2b(fmaxf(acc[s][nt][r_] + v1[nt], 0.f));
        }
    __syncthreads();

    if (w < 2) {
        floatx4 a2[2] = {zero, zero};
#pragma unroll
        for (int s = 0; s < 2; ++s)
#pragma unroll
            for (int kt = 0; kt < 3; ++kt) {
                bf16x8 a = *(const bf16x8*)&tmid[(s * 16 + lrow) * 104 + kt * 32 + lq * 8];
                a2[s] = __builtin_amdgcn_mfma_f32_16x16x32_bf16(a, fb2[kt], a2[s], 0, 0, 0);
            }
        // direct fp32 fragment stores (4 rows x 16 cols per instr; no amplification per round-4 evidence)
#pragma unroll
        for (int s = 0; s < 2; ++s) {
            int col = w * 16 + lrow;
#pragma unroll
            for (int r_ = 0; r_ < 4; ++r_)
                out_edges[(size_t)(mt * 32 + s * 16 + lq * 4 + r_) * 32 + col] = fmaxf(a2[s][r_] + v2, 0.f);
        }
    }
}

extern "C" void kernel_launch(void* const* d_in, const int* in_sizes, int n_in,
                              void* d_out, int out_size, void* d_ws, size_t ws_size,
                              hipStream_t stream) {
    const float* nodes = (const float*)d_in[0];
    const float* edges = (const float*)d_in[1];
    const float* Wan1 = (const float*)d_in[2];  const float* ban1 = (const float*)d_in[3];
    const float* Wan2 = (const float*)d_in[4];  const float* ban2 = (const float*)d_in[5];
    const float* Wln1 = (const float*)d_in[6];  const float* bln1 = (const float*)d_in[7];
    const float* Wln2 = (const float*)d_in[8];  const float* bln2 = (const float*)d_in[9];
    const float* Wae1 = (const float*)d_in[10]; const float* bae1 = (const float*)d_in[11];
    const float* Wae2 = (const float*)d_in[12]; const float* bae2 = (const float*)d_in[13];
    const float* Wle1 = (const float*)d_in[14]; const float* ble1 = (const float*)d_in[15];
    const float* Wle2 = (const float*)d_in[16]; const float* ble2 = (const float*)d_in[17];

    char* ws = (char*)d_ws;
    size_t o = 0;
    auto alloc = [&](size_t bytes) -> void* {
        void* r = ws + o;
        o += (bytes + 255) & ~(size_t)255;
        return r;
    };
    ushort_t* hn     = (ushort_t*)alloc((size_t)MROWS * 128 * 2);
    ushort_t* he     = (ushort_t*)alloc((size_t)MROWS * 64 * 2);
    ushort_t* ein    = (ushort_t*)alloc((size_t)MROWS * 96 * 2);
    ushort_t* nodesb = (ushort_t*)alloc((size_t)2 * NN * 64 * 2);
    ushort_t* edgesb = (ushort_t*)alloc((size_t)MROWS * 32 * 2);
    ushort_t* pan1 = (ushort_t*)alloc(160 * 256 * 2);
    ushort_t* pan2 = (ushort_t*)alloc(256 * 128 * 2);
    ushort_t* pae1 = (ushort_t*)alloc(96 * 128 * 2);
    ushort_t* pae2 = (ushort_t*)alloc(128 * 64 * 2);
    ushort_t* ple1 = (ushort_t*)alloc(96 * 96 * 2);
    ushort_t* ple2 = (ushort_t*)alloc(96 * 32 * 2);
    ushort_t* pln1 = (ushort_t*)alloc(192 * 192 * 2);
    ushort_t* pln2 = (ushort_t*)alloc(192 * 64 * 2);

    float* out_nodes = (float*)d_out;
    float* out_edges = (float*)d_out + 2 * NN * 64;

    k_pack<<<2751, 256, 0, stream>>>(Wan1, Wan2, Wae1, Wae2, Wle1, Wle2, Wln1, Wln2,
                                     nodes, edges,
                                     pan1, pan2, pae1, pae2, ple1, ple2, pln1, pln2,
                                     nodesb, edgesb);
    k_node_agg<<<504, 512, 0, stream>>>(nodesb, edgesb, pan1, ban1, pan2, ban2, hn, 2015);
    k_edge_agg<<<504, 512, 0, stream>>>(nodesb, edgesb, pae1, bae1, pae2, bae2, he, 2015);
    k_fuse3<<<4096, 192, 0, stream>>>(hn, nodes, pln1, bln1, pln2, bln2, out_nodes,
                                      he, edgesb, ein);
    k_le12<<<2015, 192, 0, stream>>>(ein, ple1, ble1, ple2, ble2, out_edges);

    (void)in_sizes; (void)n_in; (void)out_size; (void)ws_size;
}